// Round 5
// baseline (628.445 us; speedup 1.0000x reference)
//
#include <hip/hip_runtime.h>
#include <hip/hip_bf16.h>

typedef __attribute__((ext_vector_type(8))) short short8;
typedef __attribute__((ext_vector_type(4))) short short4v;
typedef __attribute__((ext_vector_type(4))) float floatx4;
typedef __attribute__((ext_vector_type(4))) int int4v;

#define XSTR 136   // bf16 token-major tile stride (272B rows, 16B-aligned)
#define SSTR 132   // fp32 out-stage stride (16B-aligned rows)
#define MSTR 132   // fp32 xr stride in fused kernel (16B-aligned rows)

static __device__ __forceinline__ short f2b(float f) {
    __hip_bfloat16 h = __float2bfloat16(f);
    return *reinterpret_cast<short*>(&h);
}
static __device__ __forceinline__ float b2f(short s) {
    unsigned int u = ((unsigned int)(unsigned short)s) << 16;
    return __uint_as_float(u);
}
// pack two fp32 -> one u32 of 2 bf16 (lo in bits 0..15)
static __device__ __forceinline__ int pk2(float lo, float hi) {
    return (int)((((unsigned)(unsigned short)f2b(hi)) << 16) |
                 (unsigned)(unsigned short)f2b(lo));
}
static __device__ __forceinline__ short8 mk8(int a, int b, int c, int d) {
    int4v t; t[0] = a; t[1] = b; t[2] = c; t[3] = d;
    return *reinterpret_cast<short8*>(&t);
}

// ---------------- weight cast (keeps [n][k] row-major = MFMA A/B-operand layout) -----
__global__ __launch_bounds__(256) void prep_weights(
    const float* __restrict__ wq0, const float* __restrict__ wkv0,
    const float* __restrict__ wq1, const float* __restrict__ wkv1,
    const float* __restrict__ wq2, const float* __restrict__ wkv2,
    const float* __restrict__ wout0, const float* __restrict__ wout1,
    const float* __restrict__ wout2, const float* __restrict__ w1,
    const float* __restrict__ w2, short* __restrict__ dst)
{
    const int g = blockIdx.x * 256 + threadIdx.x;  // grid exactly covers 229376
    const float* wqs[3]  = { wq0, wq1, wq2 };
    const float* wkvs[3] = { wkv0, wkv1, wkv2 };
    const float* rest[5] = { wout0, wout1, wout2, w1, w2 };
    float val;
    if (g < 147456) {
        const int a = g / 49152, l = g % 49152;
        val = (l < 16384) ? wqs[a][l] : wkvs[a][l - 16384];
    } else {
        const int l = g - 147456;
        val = rest[l >> 14][l & 16383];
    }
    dst[g] = f2b(val);
}

// ---------------- x2 = 2x + px + py + pz, channels-last bf16 -------------------------
__global__ __launch_bounds__(256) void prep_x2(
    const float* __restrict__ x, const float* __restrict__ px,
    const float* __restrict__ py, const float* __restrict__ pz,
    short* __restrict__ x2b)
{
    __shared__ float tile[128 * 49];
    const int s = blockIdx.x, tid = threadIdx.x;
    const int b = s / 2304, rr = s % 2304, xx = rr / 48, yy = rr % 48;
    for (int f = tid; f < 1536; f += 256) {
        const int c = f / 12, z4 = (f % 12) * 4;
        const floatx4 xv = *(const floatx4*)(x + (long)(b * 128 + c) * 110592 + xx * 2304 + yy * 48 + z4);
        const float pxy = px[c * 48 + xx] + py[c * 48 + yy];
        #pragma unroll
        for (int j = 0; j < 4; ++j)
            tile[c * 49 + z4 + j] = 2.0f * xv[j] + pxy + pz[c * 48 + z4 + j];
    }
    __syncthreads();
    const long tb = (long)b * 110592 + xx * 2304 + yy * 48;
    for (int f = tid; f < 1536; f += 256) {
        const int t = f >> 5, c4 = (f & 31) << 2;
        short4v pk;
        #pragma unroll
        for (int j = 0; j < 4; ++j) pk[j] = f2b(tile[(c4 + j) * 49 + t]);
        *(short4v*)(x2b + (tb + t) * 128 + c4) = pk;
    }
}

// ---------------- MFMA axial attention (axes 0/1), 512 threads / 8 waves --------------
// wave=head. Q/K/V/P never touch LDS: the producer-MFMA C layout and the consumer
// A/B-frag layout differ only by a quad-level redistribution at fixed l15, done with
// __shfl (4 per fragment, + cndmask-select where the source register depends on the
// destination quad). LDS = xs + obT + stg = 51456B -> 3 blocks/CU (6 waves/SIMD).
template<int AXIS, int ACC>
__global__ __launch_bounds__(512, 6)
void attn_axis(const short* __restrict__ x2b, const short* __restrict__ wcat,
               const short* __restrict__ woutb, const float* __restrict__ bout,
               short* __restrict__ Ab)
{
    __shared__ __align__(16) char SM[51456];
    short* xs  = (short*)SM;              // [48][XSTR] x2 tile
    short* obT = (short*)(SM + 13056);    // [48][XSTR] O tile
    float* stg = (float*)(SM + 26112);    // [48][SSTR] fp32 out stage

    const int tid  = threadIdx.x;
    const int lane = tid & 63;
    const int wave = tid >> 6;            // 0..7 == head
    const int l15  = lane & 15;
    const int quad = lane >> 4;

    const int s = blockIdx.x;
    const int b = s / 2304, rr = s % 2304, u = rr / 48, v = rr % 48;
    long base; int stride;
    if (AXIS == 0) { base = (long)b * 110592 + u * 48   + v; stride = 2304; }
    else           { base = (long)b * 110592 + u * 2304 + v; stride = 48;   }

    // ---- prefetch Q weight frags (rows wave*16..) ----
    short8 wq_[4], wk_[4], wv_[4];
    {
        const short* wp = wcat + (wave * 16 + l15) * 128 + quad * 8;
        #pragma unroll
        for (int k = 0; k < 4; ++k) wq_[k] = *(const short8*)(wp + k * 32);
    }

    // ---- stage x2 tile ----
    for (int f = tid; f < 1536; f += 512) {
        const int t = f >> 5, c4 = (f & 31) << 2;
        *(short4v*)(xs + t * XSTR + c4) =
            *(const short4v*)(x2b + (base + (long)t * stride) * 128 + c4);
    }
    __syncthreads();

    // ---- token frags (usable as A or B operand: identical lane mapping) ----
    short8 af[3][4];
    #pragma unroll
    for (int ct = 0; ct < 3; ++ct)
        #pragma unroll
        for (int k = 0; k < 4; ++k)
            af[ct][k] = *(const short8*)(xs + (ct * 16 + l15) * XSTR + k * 32 + quad * 8);

    // ---- QKV GEMMs -> packed bf16 pairs in registers ----
    int qpk[3][2], kpk[3][2], vpk[3][2];
    {   // Q (swapped): lane(q',l15) gets Q[feat 4q'+g][token ct*16+l15]; prefetch K wts
        const short* wp = wcat + ((wave + 8) * 16 + l15) * 128 + quad * 8;
        #pragma unroll
        for (int k = 0; k < 4; ++k) wk_[k] = *(const short8*)(wp + k * 32);
        floatx4 acc[3] = {{0,0,0,0},{0,0,0,0},{0,0,0,0}};
        #pragma unroll
        for (int ct = 0; ct < 3; ++ct)
            #pragma unroll
            for (int k = 0; k < 4; ++k)
                acc[ct] = __builtin_amdgcn_mfma_f32_16x16x32_bf16(wq_[k], af[ct][k], acc[ct], 0, 0, 0);
        #pragma unroll
        for (int ct = 0; ct < 3; ++ct) {
            qpk[ct][0] = pk2(acc[ct][0] * 0.25f, acc[ct][1] * 0.25f);
            qpk[ct][1] = pk2(acc[ct][2] * 0.25f, acc[ct][3] * 0.25f);
        }
    }
    {   // K (swapped); prefetch V weights
        const short* wp = wcat + ((wave + 16) * 16 + l15) * 128 + quad * 8;
        #pragma unroll
        for (int k = 0; k < 4; ++k) wv_[k] = *(const short8*)(wp + k * 32);
        floatx4 acc[3] = {{0,0,0,0},{0,0,0,0},{0,0,0,0}};
        #pragma unroll
        for (int ct = 0; ct < 3; ++ct)
            #pragma unroll
            for (int k = 0; k < 4; ++k)
                acc[ct] = __builtin_amdgcn_mfma_f32_16x16x32_bf16(wk_[k], af[ct][k], acc[ct], 0, 0, 0);
        #pragma unroll
        for (int ct = 0; ct < 3; ++ct) {
            kpk[ct][0] = pk2(acc[ct][0], acc[ct][1]);
            kpk[ct][1] = pk2(acc[ct][2], acc[ct][3]);
        }
    }
    {   // V (original): lane(q',l15) gets V[token mt*16+4q'+g][feat hb+l15]
        floatx4 acc[3] = {{0,0,0,0},{0,0,0,0},{0,0,0,0}};
        #pragma unroll
        for (int mt = 0; mt < 3; ++mt)
            #pragma unroll
            for (int k = 0; k < 4; ++k)
                acc[mt] = __builtin_amdgcn_mfma_f32_16x16x32_bf16(af[mt][k], wv_[k], acc[mt], 0, 0, 0);
        #pragma unroll
        for (int mt = 0; mt < 3; ++mt) {
            vpk[mt][0] = pk2(acc[mt][0], acc[mt][1]);
            vpk[mt][1] = pk2(acc[mt][2], acc[mt][3]);
        }
    }

    // ---- build MFMA fragments via cross-lane shuffles ----
    const short8 Z8 = {0,0,0,0,0,0,0,0};
    const int qm = quad & 1;
    const int s0 = l15 + 32 * qm, s1 = s0 + 16;   // producer lanes q'=2(q&1), 2(q&1)+1
    const bool hiq = quad >= 2;
    short8 aqf[3], akf[3];
    #pragma unroll
    for (int t = 0; t < 3; ++t) {
        short8 q8 = mk8(__shfl(qpk[t][0], s0, 64), __shfl(qpk[t][1], s0, 64),
                        __shfl(qpk[t][0], s1, 64), __shfl(qpk[t][1], s1, 64));
        aqf[t] = hiq ? Z8 : q8;   // zero B-operand k-rows >=16 (K=16 MFMA)
        akf[t] = mk8(__shfl(kpk[t][0], s0, 64), __shfl(kpk[t][1], s0, 64),
                     __shfl(kpk[t][0], s1, 64), __shfl(kpk[t][1], s1, 64));
    }
    short8 av0, av1;
    {
        const int t00 = __shfl(vpk[0][0], s0, 64), t01 = __shfl(vpk[0][1], s0, 64);
        const int t02 = __shfl(vpk[0][0], s1, 64), t03 = __shfl(vpk[0][1], s1, 64);
        const int t10 = __shfl(vpk[1][0], s0, 64), t11 = __shfl(vpk[1][1], s0, 64);
        const int t12 = __shfl(vpk[1][0], s1, 64), t13 = __shfl(vpk[1][1], s1, 64);
        av0 = mk8(hiq ? t10 : t00, hiq ? t11 : t01, hiq ? t12 : t02, hiq ? t13 : t03);
        av1 = mk8(__shfl(vpk[2][0], s0, 64), __shfl(vpk[2][1], s0, 64),
                  __shfl(vpk[2][0], s1, 64), __shfl(vpk[2][1], s1, 64));
    }

    // ---- attention (pure register dataflow) ----
    const int hb = wave * 16;
    #pragma unroll
    for (int it = 0; it < 3; ++it) {
        floatx4 sc[3];
        #pragma unroll
        for (int jt = 0; jt < 3; ++jt) {
            floatx4 z = {0,0,0,0};
            sc[jt] = __builtin_amdgcn_mfma_f32_16x16x32_bf16(akf[jt], aqf[it], z, 0, 0, 0);
        }
        // softmax over j (no max-shift: scores ~N(0,0.36))
        float e[3][4]; float ssum = 0.f;
        #pragma unroll
        for (int jt = 0; jt < 3; ++jt)
            #pragma unroll
            for (int g = 0; g < 4; ++g) { e[jt][g] = __expf(sc[jt][g]); ssum += e[jt][g]; }
        ssum += __shfl_xor(ssum, 16, 64);
        ssum += __shfl_xor(ssum, 32, 64);
        const float inv = 1.0f / ssum;
        int ppk[3][2];
        #pragma unroll
        for (int jt = 0; jt < 3; ++jt) {
            ppk[jt][0] = pk2(e[jt][0] * inv, e[jt][1] * inv);
            ppk[jt][1] = pk2(e[jt][2] * inv, e[jt][3] * inv);
        }
        const int a0 = __shfl(ppk[0][0], s0, 64), a1 = __shfl(ppk[0][1], s0, 64);
        const int a2 = __shfl(ppk[0][0], s1, 64), a3 = __shfl(ppk[0][1], s1, 64);
        const int c0 = __shfl(ppk[1][0], s0, 64), c1 = __shfl(ppk[1][1], s0, 64);
        const int c2 = __shfl(ppk[1][0], s1, 64), c3 = __shfl(ppk[1][1], s1, 64);
        short8 ap  = mk8(hiq ? c0 : a0, hiq ? c1 : a1, hiq ? c2 : a2, hiq ? c3 : a3);
        short8 ap1 = mk8(__shfl(ppk[2][0], s0, 64), __shfl(ppk[2][1], s0, 64),
                         __shfl(ppk[2][0], s1, 64), __shfl(ppk[2][1], s1, 64));
        if (hiq) ap1 = Z8;   // zero B-operand k-rows >=16 (j-block 2 has 16 keys)
        floatx4 o = {0,0,0,0};
        o = __builtin_amdgcn_mfma_f32_16x16x32_bf16(av0, ap,  o, 0, 0, 0);
        o = __builtin_amdgcn_mfma_f32_16x16x32_bf16(av1, ap1, o, 0, 0, 0);
        short4v ok;
        #pragma unroll
        for (int g = 0; g < 4; ++g) ok[g] = f2b(o[g]);
        *(short4v*)(obT + (it * 16 + l15) * XSTR + hb + quad * 4) = ok;
    }
    __syncthreads();

    // ---- A prefetch for the RMW (latency hidden under out-proj) ----
    short4v apre[3];
    if (ACC) {
        #pragma unroll
        for (int i = 0; i < 3; ++i) {
            const int f = tid + i * 512;
            const int t = f >> 5, c4 = (f & 31) << 2;
            apre[i] = *(const short4v*)(Ab + (base + (long)t * stride) * 128 + c4);
        }
    }

    // ---- output projection (swapped): C[outfeat, token] -> vectorized stg ----
    {
        short8 afo[3][4];
        #pragma unroll
        for (int ct = 0; ct < 3; ++ct)
            #pragma unroll
            for (int k = 0; k < 4; ++k)
                afo[ct][k] = *(const short8*)(obT + (ct * 16 + l15) * XSTR + k * 32 + quad * 8);
        const int nf = wave * 16;
        short8 wo_[4];
        #pragma unroll
        for (int k = 0; k < 4; ++k)
            wo_[k] = *(const short8*)(woutb + (nf + l15) * 128 + k * 32 + quad * 8);
        floatx4 acc[3] = {{0,0,0,0},{0,0,0,0},{0,0,0,0}};
        #pragma unroll
        for (int ct = 0; ct < 3; ++ct)
            #pragma unroll
            for (int k = 0; k < 4; ++k)
                acc[ct] = __builtin_amdgcn_mfma_f32_16x16x32_bf16(wo_[k], afo[ct][k], acc[ct], 0, 0, 0);
        const floatx4 bo4 = *(const floatx4*)(bout + nf + quad * 4);
        #pragma unroll
        for (int ct = 0; ct < 3; ++ct) {
            floatx4 ox;
            #pragma unroll
            for (int g = 0; g < 4; ++g) ox[g] = acc[ct][g] + bo4[g];
            *(floatx4*)(stg + (ct * 16 + l15) * SSTR + nf + quad * 4) = ox;
        }
    }
    __syncthreads();

    // ---- coalesced write / RMW into bf16 A ----
    #pragma unroll
    for (int i = 0; i < 3; ++i) {
        const int f = tid + i * 512;
        const int t = f >> 5, c4 = (f & 31) << 2;
        const long gi = (base + (long)t * stride) * 128 + c4;
        const floatx4 vv = *(const floatx4*)(stg + t * SSTR + c4);
        short4v out4;
        if (ACC) {
            #pragma unroll
            for (int j = 0; j < 4; ++j) out4[j] = f2b(b2f(apre[i][j]) + vv[j]);
        } else {
            #pragma unroll
            for (int j = 0; j < 4; ++j) out4[j] = f2b(vv[j]);
        }
        *(short4v*)(Ab + gi) = out4;
    }
}

// ---------------- fused axis-2 attention + residual + LN1 + MLP + LN2 + out -----------
static __device__ __forceinline__ void ln_stats132(const float* xr, float* mean_,
                                                   float* rstd_, int tid)
{
    if (tid < 192) {
        const int r = tid >> 2, p = tid & 3;
        const float* row = xr + r * MSTR + p * 32;
        float s1 = 0.f, s2 = 0.f;
        #pragma unroll
        for (int c0 = 0; c0 < 32; ++c0) {
            const float xv = row[(c0 + p * 8) & 31];
            s1 += xv; s2 += xv * xv;
        }
        s1 += __shfl_xor(s1, 1, 64); s1 += __shfl_xor(s1, 2, 64);
        s2 += __shfl_xor(s2, 1, 64); s2 += __shfl_xor(s2, 2, 64);
        if (p == 0) {
            const float m = s1 * (1.f / 128.f);
            mean_[r] = m;
            rstd_[r] = rsqrtf(s2 * (1.f / 128.f) - m * m + 1e-5f);
        }
    }
}

__global__ __launch_bounds__(512, 6)
void attn2_mlp(const short* __restrict__ x2b, const short* __restrict__ Ab,
               const short* __restrict__ wcat, const short* __restrict__ woutb,
               const float* __restrict__ bout,
               const float* __restrict__ ln_g, const float* __restrict__ ln_b,
               const short* __restrict__ w1b, const float* __restrict__ b1,
               const short* __restrict__ w2b, const float* __restrict__ b2,
               float* __restrict__ out)
{
    __shared__ __align__(16) char SM[53888];
    short* xs   = (short*)SM;              // [48][XSTR] x2 stage (live thru residual)
    short* obT  = (short*)(SM + 13056);    // [48][XSTR] O tile
    float* xr   = (float*)(SM + 26112);    // [48][MSTR] fp32, 25344
    short* lnb  = (short*)SM;              // aliases xs (dead after residual)
    short* hbuf = (short*)(SM + 13056);    // aliases obT (dead after out-proj frags)
    float* gs   = (float*)(SM + 51456);
    float* bs   = (float*)(SM + 51968);
    float* b1s  = (float*)(SM + 52480);
    float* b2s  = (float*)(SM + 52992);
    float* mean_ = (float*)(SM + 53504);
    float* rstd_ = (float*)(SM + 53696);

    const int tid  = threadIdx.x;
    const int lane = tid & 63;
    const int wave = tid >> 6;             // 0..7 == head
    const int l15  = lane & 15;
    const int quad = lane >> 4;

    const int s = blockIdx.x;
    const int b = s / 2304, rr = s % 2304, xx = rr / 48, yy = rr % 48;
    const long tb = (long)b * 110592 + xx * 2304 + yy * 48;

    // ---- prefetch Q weight frags ----
    short8 wq_[4], wk_[4], wv_[4];
    {
        const short* wp = wcat + (wave * 16 + l15) * 128 + quad * 8;
        #pragma unroll
        for (int k = 0; k < 4; ++k) wq_[k] = *(const short8*)(wp + k * 32);
    }

    if (tid < 128) {
        gs[tid] = ln_g[tid]; bs[tid] = ln_b[tid];
        b1s[tid] = b1[tid];  b2s[tid] = b2[tid];
    }
    // ---- stage x2 tile (also read back for the residual later) ----
    for (int f = tid; f < 1536; f += 512) {
        const int t = f >> 5, c4 = (f & 31) << 2;
        *(short4v*)(xs + t * XSTR + c4) = *(const short4v*)(x2b + (tb + t) * 128 + c4);
    }
    __syncthreads();

    // ---- token frags ----
    short8 af[3][4];
    #pragma unroll
    for (int ct = 0; ct < 3; ++ct)
        #pragma unroll
        for (int k = 0; k < 4; ++k)
            af[ct][k] = *(const short8*)(xs + (ct * 16 + l15) * XSTR + k * 32 + quad * 8);

    // ---- QKV GEMMs -> packed registers ----
    int qpk[3][2], kpk[3][2], vpk[3][2];
    {
        const short* wp = wcat + ((wave + 8) * 16 + l15) * 128 + quad * 8;
        #pragma unroll
        for (int k = 0; k < 4; ++k) wk_[k] = *(const short8*)(wp + k * 32);
        floatx4 acc[3] = {{0,0,0,0},{0,0,0,0},{0,0,0,0}};
        #pragma unroll
        for (int ct = 0; ct < 3; ++ct)
            #pragma unroll
            for (int k = 0; k < 4; ++k)
                acc[ct] = __builtin_amdgcn_mfma_f32_16x16x32_bf16(wq_[k], af[ct][k], acc[ct], 0, 0, 0);
        #pragma unroll
        for (int ct = 0; ct < 3; ++ct) {
            qpk[ct][0] = pk2(acc[ct][0] * 0.25f, acc[ct][1] * 0.25f);
            qpk[ct][1] = pk2(acc[ct][2] * 0.25f, acc[ct][3] * 0.25f);
        }
    }
    {
        const short* wp = wcat + ((wave + 16) * 16 + l15) * 128 + quad * 8;
        #pragma unroll
        for (int k = 0; k < 4; ++k) wv_[k] = *(const short8*)(wp + k * 32);
        floatx4 acc[3] = {{0,0,0,0},{0,0,0,0},{0,0,0,0}};
        #pragma unroll
        for (int ct = 0; ct < 3; ++ct)
            #pragma unroll
            for (int k = 0; k < 4; ++k)
                acc[ct] = __builtin_amdgcn_mfma_f32_16x16x32_bf16(wk_[k], af[ct][k], acc[ct], 0, 0, 0);
        #pragma unroll
        for (int ct = 0; ct < 3; ++ct) {
            kpk[ct][0] = pk2(acc[ct][0], acc[ct][1]);
            kpk[ct][1] = pk2(acc[ct][2], acc[ct][3]);
        }
    }
    {
        floatx4 acc[3] = {{0,0,0,0},{0,0,0,0},{0,0,0,0}};
        #pragma unroll
        for (int mt = 0; mt < 3; ++mt)
            #pragma unroll
            for (int k = 0; k < 4; ++k)
                acc[mt] = __builtin_amdgcn_mfma_f32_16x16x32_bf16(af[mt][k], wv_[k], acc[mt], 0, 0, 0);
        #pragma unroll
        for (int mt = 0; mt < 3; ++mt) {
            vpk[mt][0] = pk2(acc[mt][0], acc[mt][1]);
            vpk[mt][1] = pk2(acc[mt][2], acc[mt][3]);
        }
    }

    // ---- build fragments via shuffles ----
    const short8 Z8 = {0,0,0,0,0,0,0,0};
    const int qm = quad & 1;
    const int s0 = l15 + 32 * qm, s1 = s0 + 16;
    const bool hiq = quad >= 2;
    short8 aqf[3], akf[3];
    #pragma unroll
    for (int t = 0; t < 3; ++t) {
        short8 q8 = mk8(__shfl(qpk[t][0], s0, 64), __shfl(qpk[t][1], s0, 64),
                        __shfl(qpk[t][0], s1, 64), __shfl(qpk[t][1], s1, 64));
        aqf[t] = hiq ? Z8 : q8;
        akf[t] = mk8(__shfl(kpk[t][0], s0, 64), __shfl(kpk[t][1], s0, 64),
                     __shfl(kpk[t][0], s1, 64), __shfl(kpk[t][1], s1, 64));
    }
    short8 av0, av1;
    {
        const int t00 = __shfl(vpk[0][0], s0, 64), t01 = __shfl(vpk[0][1], s0, 64);
        const int t02 = __shfl(vpk[0][0], s1, 64), t03 = __shfl(vpk[0][1], s1, 64);
        const int t10 = __shfl(vpk[1][0], s0, 64), t11 = __shfl(vpk[1][1], s0, 64);
        const int t12 = __shfl(vpk[1][0], s1, 64), t13 = __shfl(vpk[1][1], s1, 64);
        av0 = mk8(hiq ? t10 : t00, hiq ? t11 : t01, hiq ? t12 : t02, hiq ? t13 : t03);
        av1 = mk8(__shfl(vpk[2][0], s0, 64), __shfl(vpk[2][1], s0, 64),
                  __shfl(vpk[2][0], s1, 64), __shfl(vpk[2][1], s1, 64));
    }

    // ---- attention ----
    const int hb = wave * 16;
    #pragma unroll
    for (int it = 0; it < 3; ++it) {
        floatx4 sc[3];
        #pragma unroll
        for (int jt = 0; jt < 3; ++jt) {
            floatx4 z = {0,0,0,0};
            sc[jt] = __builtin_amdgcn_mfma_f32_16x16x32_bf16(akf[jt], aqf[it], z, 0, 0, 0);
        }
        float e[3][4]; float ssum = 0.f;
        #pragma unroll
        for (int jt = 0; jt < 3; ++jt)
            #pragma unroll
            for (int g = 0; g < 4; ++g) { e[jt][g] = __expf(sc[jt][g]); ssum += e[jt][g]; }
        ssum += __shfl_xor(ssum, 16, 64);
        ssum += __shfl_xor(ssum, 32, 64);
        const float inv = 1.0f / ssum;
        int ppk[3][2];
        #pragma unroll
        for (int jt = 0; jt < 3; ++jt) {
            ppk[jt][0] = pk2(e[jt][0] * inv, e[jt][1] * inv);
            ppk[jt][1] = pk2(e[jt][2] * inv, e[jt][3] * inv);
        }
        const int a0 = __shfl(ppk[0][0], s0, 64), a1 = __shfl(ppk[0][1], s0, 64);
        const int a2 = __shfl(ppk[0][0], s1, 64), a3 = __shfl(ppk[0][1], s1, 64);
        const int c0 = __shfl(ppk[1][0], s0, 64), c1 = __shfl(ppk[1][1], s0, 64);
        const int c2 = __shfl(ppk[1][0], s1, 64), c3 = __shfl(ppk[1][1], s1, 64);
        short8 ap  = mk8(hiq ? c0 : a0, hiq ? c1 : a1, hiq ? c2 : a2, hiq ? c3 : a3);
        short8 ap1 = mk8(__shfl(ppk[2][0], s0, 64), __shfl(ppk[2][1], s0, 64),
                         __shfl(ppk[2][0], s1, 64), __shfl(ppk[2][1], s1, 64));
        if (hiq) ap1 = Z8;
        floatx4 o = {0,0,0,0};
        o = __builtin_amdgcn_mfma_f32_16x16x32_bf16(av0, ap,  o, 0, 0, 0);
        o = __builtin_amdgcn_mfma_f32_16x16x32_bf16(av1, ap1, o, 0, 0, 0);
        short4v ok;
        #pragma unroll
        for (int g = 0; g < 4; ++g) ok[g] = f2b(o[g]);
        *(short4v*)(obT + (it * 16 + l15) * XSTR + hb + quad * 4) = ok;
    }
    __syncthreads();

    // ---- A prefetch (consumed in residual; latency hidden under out-proj) ----
    short4v apre[3];
    #pragma unroll
    for (int i = 0; i < 3; ++i) {
        const int f = tid + i * 512;
        const int t = f >> 5, c4 = (f & 31) << 2;
        apre[i] = *(const short4v*)(Ab + (tb + t) * 128 + c4);
    }

    const int nf = wave * 16;
    // ---- output projection (swapped) -> xr fp32 vectorized ----
    {
        short8 afo[3][4];
        #pragma unroll
        for (int ct = 0; ct < 3; ++ct)
            #pragma unroll
            for (int k = 0; k < 4; ++k)
                afo[ct][k] = *(const short8*)(obT + (ct * 16 + l15) * XSTR + k * 32 + quad * 8);
        short8 wo_[4];
        #pragma unroll
        for (int k = 0; k < 4; ++k)
            wo_[k] = *(const short8*)(woutb + (nf + l15) * 128 + k * 32 + quad * 8);
        floatx4 acc[3] = {{0,0,0,0},{0,0,0,0},{0,0,0,0}};
        #pragma unroll
        for (int ct = 0; ct < 3; ++ct)
            #pragma unroll
            for (int k = 0; k < 4; ++k)
                acc[ct] = __builtin_amdgcn_mfma_f32_16x16x32_bf16(wo_[k], afo[ct][k], acc[ct], 0, 0, 0);
        const floatx4 bo4 = *(const floatx4*)(bout + nf + quad * 4);
        #pragma unroll
        for (int ct = 0; ct < 3; ++ct) {
            floatx4 ox;
            #pragma unroll
            for (int g = 0; g < 4; ++g) ox[g] = acc[ct][g] + bo4[g];
            *(floatx4*)(xr + (ct * 16 + l15) * MSTR + nf + quad * 4) = ox;
        }
    }
    __syncthreads();

    // ---- residual + LN1 stats fused: xr += A(prefetched) + x2(from xs) ----
    #pragma unroll
    for (int i = 0; i < 3; ++i) {
        const int f = tid + i * 512;
        const int t = f >> 5, c4 = (f & 31) << 2;
        floatx4 xv = *(const floatx4*)(xr + t * MSTR + c4);
        const short4v x4 = *(const short4v*)(xs + t * XSTR + c4);
        float s1 = 0.f, s2 = 0.f;
        #pragma unroll
        for (int j = 0; j < 4; ++j) {
            xv[j] += b2f(apre[i][j]) + b2f(x4[j]);
            s1 += xv[j]; s2 += xv[j] * xv[j];
        }
        *(floatx4*)(xr + t * MSTR + c4) = xv;
        s1 += __shfl_xor(s1, 1, 64);  s2 += __shfl_xor(s2, 1, 64);
        s1 += __shfl_xor(s1, 2, 64);  s2 += __shfl_xor(s2, 2, 64);
        s1 += __shfl_xor(s1, 4, 64);  s2 += __shfl_xor(s2, 4, 64);
        s1 += __shfl_xor(s1, 8, 64);  s2 += __shfl_xor(s2, 8, 64);
        s1 += __shfl_xor(s1, 16, 64); s2 += __shfl_xor(s2, 16, 64);
        if ((lane & 31) == 0) {
            const float m = s1 * (1.f / 128.f);
            mean_[t] = m;
            rstd_[t] = rsqrtf(s2 * (1.f / 128.f) - m * m + 1e-5f);
        }
    }
    __syncthreads();

    // ---- LN1 -> lnb (aliases xs; xs reads finished before this barrier) ----
    for (int f = tid; f < 6144; f += 512) {
        const int t = f >> 7, c = f & 127;
        lnb[t * XSTR + c] = f2b((xr[t * MSTR + c] - mean_[t]) * rstd_[t] * gs[c] + bs[c]);
    }
    __syncthreads();

    // ---- MLP GEMM1 (swapped) + relu -> hbuf packed ----
    {
        short8 afl[3][4];
        #pragma unroll
        for (int ct = 0; ct < 3; ++ct)
            #pragma unroll
            for (int k = 0; k < 4; ++k)
                afl[ct][k] = *(const short8*)(lnb + (ct * 16 + l15) * XSTR + k * 32 + quad * 8);
        short8 w1_[4];
        #pragma unroll
        for (int k = 0; k < 4; ++k)
            w1_[k] = *(const short8*)(w1b + (nf + l15) * 128 + k * 32 + quad * 8);
        floatx4 acc[3] = {{0,0,0,0},{0,0,0,0},{0,0,0,0}};
        #pragma unroll
        for (int ct = 0; ct < 3; ++ct)
            #pragma unroll
            for (int k = 0; k < 4; ++k)
                acc[ct] = __builtin_amdgcn_mfma_f32_16x16x32_bf16(w1_[k], afl[ct][k], acc[ct], 0, 0, 0);
        const floatx4 bb4 = *(const floatx4*)(b1s + nf + quad * 4);
        #pragma unroll
        for (int ct = 0; ct < 3; ++ct) {
            short4v hk;
            #pragma unroll
            for (int g = 0; g < 4; ++g) hk[g] = f2b(fmaxf(acc[ct][g] + bb4[g], 0.f));
            *(short4v*)(hbuf + (ct * 16 + l15) * XSTR + nf + quad * 4) = hk;
        }
    }
    __syncthreads();

    // ---- MLP GEMM2 (swapped) + inner residual (fp32-recomputed ln1), vectorized ----
    {
        short8 afh[3][4];
        #pragma unroll
        for (int ct = 0; ct < 3; ++ct)
            #pragma unroll
            for (int k = 0; k < 4; ++k)
                afh[ct][k] = *(const short8*)(hbuf + (ct * 16 + l15) * XSTR + k * 32 + quad * 8);
        short8 w2_[4];
        #pragma unroll
        for (int k = 0; k < 4; ++k)
            w2_[k] = *(const short8*)(w2b + (nf + l15) * 128 + k * 32 + quad * 8);
        floatx4 acc[3] = {{0,0,0,0},{0,0,0,0},{0,0,0,0}};
        #pragma unroll
        for (int ct = 0; ct < 3; ++ct)
            #pragma unroll
            for (int k = 0; k < 4; ++k)
                acc[ct] = __builtin_amdgcn_mfma_f32_16x16x32_bf16(w2_[k], afh[ct][k], acc[ct], 0, 0, 0);
        const floatx4 bb4 = *(const floatx4*)(b2s + nf + quad * 4);
        const floatx4 g4  = *(const floatx4*)(gs + nf + quad * 4);
        const floatx4 be4 = *(const floatx4*)(bs + nf + quad * 4);
        #pragma unroll
        for (int ct = 0; ct < 3; ++ct) {
            const int t = ct * 16 + l15;
            const float mn = mean_[t], rs = rstd_[t];
            floatx4 xv = *(const floatx4*)(xr + t * MSTR + nf + quad * 4);
            floatx4 nx;
            #pragma unroll
            for (int g = 0; g < 4; ++g) {
                const float ln1 = (xv[g] - mn) * rs * g4[g] + be4[g];
                nx[g] = acc[ct][g] + bb4[g] + ln1;
            }
            *(floatx4*)(xr + t * MSTR + nf + quad * 4) = nx;
        }
    }
    __syncthreads();
    ln_stats132(xr, mean_, rstd_, tid);
    __syncthreads();

    // ---- channels-first vectorized output ----
    for (int f = tid; f < 1536; f += 512) {
        const int c = f / 12, z4 = (f % 12) * 4;
        floatx4 o4;
        #pragma unroll
        for (int j = 0; j < 4; ++j)
            o4[j] = (xr[(z4 + j) * MSTR + c] - mean_[z4 + j]) * rstd_[z4 + j] * gs[c] + bs[c];
        *(floatx4*)(out + (long)(b * 128 + c) * 110592 + xx * 2304 + yy * 48 + z4) = o4;
    }
}

// -------------------------------------------------------------------------------------
extern "C" void kernel_launch(void* const* d_in, const int* in_sizes, int n_in,
                              void* d_out, int out_size, void* d_ws, size_t ws_size,
                              hipStream_t stream)
{
    const float* x    = (const float*)d_in[0];
    const float* px   = (const float*)d_in[1];
    const float* py   = (const float*)d_in[2];
    const float* pz   = (const float*)d_in[3];
    const float* wq[3]   = { (const float*)d_in[4],  (const float*)d_in[8],  (const float*)d_in[12] };
    const float* wkv[3]  = { (const float*)d_in[5],  (const float*)d_in[9],  (const float*)d_in[13] };
    const float* wout[3] = { (const float*)d_in[6],  (const float*)d_in[10], (const float*)d_in[14] };
    const float* bout[3] = { (const float*)d_in[7],  (const float*)d_in[11], (const float*)d_in[15] };
    const float* ln_g = (const float*)d_in[16];
    const float* ln_b = (const float*)d_in[17];
    const float* w1   = (const float*)d_in[18];
    const float* b1   = (const float*)d_in[19];
    const float* w2   = (const float*)d_in[20];
    const float* b2   = (const float*)d_in[21];

    // ws: A bf16 (56,623,104 B) | weights bf16 (458,752 B) | x2b bf16 (56,623,104 B)
    short* Ab  = (short*)d_ws;
    short* wb  = (short*)((char*)d_ws + 56623104);
    short* x2b = (short*)((char*)d_ws + 57081856);

    prep_weights<<<896, 256, 0, stream>>>(wq[0], wkv[0], wq[1], wkv[1], wq[2], wkv[2],
                                          wout[0], wout[1], wout[2], w1, w2, wb);
    prep_x2<<<4608, 256, 0, stream>>>(x, px, py, pz, x2b);

    attn_axis<0, 0><<<4608, 512, 0, stream>>>(x2b, wb,         wb + 147456, bout[0], Ab);
    attn_axis<1, 1><<<4608, 512, 0, stream>>>(x2b, wb + 49152, wb + 163840, bout[1], Ab);

    attn2_mlp<<<4608, 512, 0, stream>>>(x2b, Ab, wb + 98304, wb + 180224, bout[2],
                                        ln_g, ln_b, wb + 196608, b1, wb + 212992, b2,
                                        (float*)d_out);
}